// Round 12
// baseline (1069.095 us; speedup 1.0000x reference)
//
#include <hip/hip_runtime.h>
#include <math.h>

#define B_    16
#define CIN   64
#define COUT  128
#define H_    128
#define W_    128
#define CI2   128            // 2*CIN (x ++ silu(x))
#define KTOT  1152           // 9 taps * CI2

typedef __bf16 bf16x8 __attribute__((ext_vector_type(8)));
typedef float  f32x4  __attribute__((ext_vector_type(4)));

#define XT_BYTES  ((size_t)B_ * H_ * W_ * CI2 * 2)   // 67,108,864
#define WC_BYTES  ((size_t)COUT * KTOT * 2)          // 294,912
#define Z_OFF     (XT_BYTES + WC_BYTES)
#define WS_NEED   (Z_OFF + 4096)

// ---------- prep 1: weights -> Wc in WAVE-FRAGMENT order ----------
__global__ __launch_bounds__(256) void w_prep(const float* __restrict__ sw,
                                              const float* __restrict__ bw,
                                              __bf16* __restrict__ wc,
                                              float* __restrict__ zp) {
    const int i = blockIdx.x * 256 + threadIdx.x;
    if (blockIdx.x == 0) zp[threadIdx.x] = 0.f;  // zeros page (1 KiB)
    if (i >= COUT * KTOT) return;
    const int co = i / KTOT, k = i - co * KTOT;
    const int tap = k >> 7, ci2 = k & 127;
    float v;
    if (ci2 < CIN) {
        const float* p = sw + ((size_t)(co * CIN + ci2) * 9 + tap) * 4;
        v = p[0] + p[1] + p[2] + p[3];
    } else {
        v = bw[(size_t)(co * CIN + (ci2 - CIN)) * 9 + tap];
    }
    const int wm = co >> 6, m = (co >> 4) & 3, l15 = co & 15;
    const int ks = (k >> 5) & 3, lq = (k >> 3) & 3, e = k & 7;
    const size_t off =
        ((size_t)(((wm * 4 + m) * 9 + tap) * 4 + ks) * 64 + lq * 16 + l15) * 8 + e;
    wc[off] = (__bf16)v;
}

// ---------- prep 2: x (NCHW fp32) -> Xt (NHWC bf16, ci2 = x ++ silu(x)) ----------
__global__ __launch_bounds__(256) void xt_prep(const float* __restrict__ x,
                                               __bf16* __restrict__ xt) {
    __shared__ __align__(16) __bf16 tile[64][136];
    const int t  = threadIdx.x;
    const int w0 = blockIdx.x * 64;
    const int h  = blockIdx.y;
    const int b  = blockIdx.z;
    const float* xb = x + ((size_t)(b * CIN) * H_ + h) * W_ + w0;
#pragma unroll
    for (int rep = 0; rep < 16; ++rep) {
        const int idx = rep * 256 + t;
        const int ci = idx >> 6, w = idx & 63;
        const float v = xb[(size_t)ci * H_ * W_ + w];
        tile[w][ci]       = (__bf16)v;
        tile[w][CIN + ci] = (__bf16)(v / (1.f + __expf(-v)));
    }
    __syncthreads();
    __bf16* ob = xt + (((size_t)b * H_ + h) * W_ + w0) * CI2;
#pragma unroll
    for (int rep = 0; rep < 4; ++rep) {
        const int idx = rep * 256 + t;
        const int w = idx >> 4, sl = idx & 15;
        *(bf16x8*)(ob + (size_t)w * CI2 + sl * 8) = *(const bf16x8*)(&tile[w][sl * 8]);
    }
}

// ---------- main: persistent 2-phase pipelined implicit-GEMM MFMA conv ----------
// 1024 persistent blocks; each owns 4 CONSECUTIVE 8h x 8w tiles (same b,hy;
// wx0..wx0+3 -> one full 128B out-line span per (co,h) row -> L2 write-merge).
// LDS: double-buffered 100-pos halo tiles (2 x 25600B = 50KB) -> 3 blocks/CU.
// Per tile: barrier -> issue stage(next half) -> compute 36 steps -> stores.
__global__ __launch_bounds__(256, 2) void kan_mfma(const __bf16* __restrict__ xt,
                                                   const __bf16* __restrict__ wc,
                                                   const float* __restrict__ zp,
                                                   float* __restrict__ out) {
    __shared__ __align__(16) char xs[2 * 100 * 256];   // 51200 B
    const int t    = threadIdx.x;
    const int lane = t & 63, wave = t >> 6;
    const int wm = wave >> 1, wn = wave & 1;
    const int l15 = lane & 15, lq = lane >> 4;

    // XCD-chunked mapping: XCD k gets contiguous wid range (1024 blocks, 8 XCDs)
    const int orig = blockIdx.x;                       // 0..1023
    const int wid  = (orig & 7) * 128 + (orig >> 3);   // bijective
    const int tile0 = wid * 4;                         // 4096 tiles total
    const int b    = tile0 >> 8;
    const int h0   = ((tile0 >> 4) & 15) * 8;
    const int wx0  = tile0 & 15;                       // multiple of 4

    const size_t xbase = (size_t)b * (H_ * W_ * CI2);

    // stage one 10x10 halo tile (1600 16B slots) into LDS half, swizzled source
#define STAGE_(half, w0s)                                                       \
    _Pragma("unroll")                                                           \
    for (int i = 0; i < 7; ++i) {                                               \
        const int s = i * 256 + t;                                              \
        if (s < 1600) {                                                         \
            const int pos = s >> 4, q = s & 15;                                 \
            const int ih = pos / 10, iw = pos - ih * 10;                        \
            const int gh = h0 + ih - 1, gw = (w0s) + iw - 1;                    \
            const int chunk = q ^ (pos & 15);                                   \
            const void* src;                                                    \
            if (gh >= 0 && gh < H_ && gw >= 0 && gw < W_)                       \
                src = (const void*)(xt + xbase +                                \
                      ((size_t)(gh * W_ + gw)) * CI2 + chunk * 8);              \
            else                                                                \
                src = (const void*)zp;                                          \
            __builtin_amdgcn_global_load_lds(                                   \
                (const __attribute__((address_space(1))) unsigned int*)src,     \
                (__attribute__((address_space(3))) unsigned int*)                \
                    (xs + (half) * 25600 + s * 16), 16, 0, 0);                  \
        }                                                                       \
    }

    // A-fragment base pointers (permuted wc layout): step s adds s*512 elems
    const __bf16* arow[4];
#pragma unroll
    for (int m = 0; m < 4; ++m)
        arow[m] = wc + ((size_t)(wm * 4 + m) * 36 * 64 + lq * 16 + l15) * 8;

    STAGE_(0, wx0 * 8);                     // prologue stage of tile 0

    for (int j = 0; j < 4; ++j) {
        const int half = j & 1;
        __syncthreads();                    // drains stage(j); syncs reads of half^1
        if (j < 3) STAGE_(half ^ 1, (wx0 + j + 1) * 8);

        const char* cb = xs + half * 25600;
        f32x4 acc[4][2] = {};

        // 36 steps: s -> tap = s>>2 (kh=tap/3, kw=tap%3), ks = s&3
#pragma unroll
        for (int s = 0; s < 36; ++s) {
            const int kh = (s >> 2) / 3, kw = (s >> 2) % 3, ks = s & 3;
            bf16x8 af[4], bfr[2];
#pragma unroll
            for (int m = 0; m < 4; ++m)
                af[m] = *(const bf16x8*)(arow[m] + (size_t)s * 512);
#pragma unroll
            for (int f2 = 0; f2 < 2; ++f2) {
                const int f = wn * 2 + f2;                       // n-frag 0..3
                const int cell = (f * 2 + (l15 >> 3) + kh) * 10 + (l15 & 7) + kw;
                const int swz  = (ks * 4 + lq) ^ (cell & 15);
                bfr[f2] = *(const bf16x8*)(cb + cell * 256 + swz * 16);
            }
#pragma unroll
            for (int m = 0; m < 4; ++m)
#pragma unroll
                for (int f2 = 0; f2 < 2; ++f2)
                    acc[m][f2] = __builtin_amdgcn_mfma_f32_16x16x32_bf16(
                        af[m], bfr[f2], acc[m][f2], 0, 0, 0);
        }

        // epilogue tile j: D row = co (lq*4+r), col = pos ((wn*2+f2)*16+l15)
        const int w0j = (wx0 + j) * 8;
        float* ob = out + (size_t)b * COUT * H_ * W_;
#pragma unroll
        for (int m = 0; m < 4; ++m) {
            const int co = wm * 64 + m * 16 + lq * 4;
#pragma unroll
            for (int f2 = 0; f2 < 2; ++f2) {
                const int ph = (wn * 2 + f2) * 2 + (l15 >> 3);
                const int pw = l15 & 7;
                float* p = ob + ((size_t)co * H_ + (h0 + ph)) * W_ + (w0j + pw);
#pragma unroll
                for (int r = 0; r < 4; ++r)
                    p[(size_t)r * H_ * W_] = acc[m][f2][r];
            }
        }
    }
#undef STAGE_
}

// ---------- fallback (round-0 fp32 path, used only if ws too small) ----------
#define TS   16
#define COB  8
#define TIN  18
__global__ __launch_bounds__(256) void spline_sum_kernel(const float* __restrict__ sw,
                                                         float* __restrict__ wsum) {
    int i = blockIdx.x * 256 + threadIdx.x;
    if (i < COUT * CIN * 9) {
        const float4 v = *reinterpret_cast<const float4*>(sw + (size_t)i * 4);
        wsum[i] = v.x + v.y + v.z + v.w;
    }
}
__global__ __launch_bounds__(256) void kan_conv(const float* __restrict__ x,
                                                const float* __restrict__ wsp,
                                                const float* __restrict__ wb,
                                                float* __restrict__ out) {
    __shared__ float xsm[TIN][20];
    __shared__ float ssm[TIN][20];
    const int t = threadIdx.x, tx = t & 15, ty = t >> 4;
    const int w0 = (blockIdx.x & 7) * TS, h0 = (blockIdx.x >> 3) * TS;
    const int co0 = blockIdx.y * COB, b = blockIdx.z;
    float acc[COB];
#pragma unroll
    for (int i = 0; i < COB; ++i) acc[i] = 0.f;
    const float* xb = x + (size_t)b * CIN * H_ * W_;
    for (int ci = 0; ci < CIN; ++ci) {
        __syncthreads();
        const float* xc = xb + (size_t)ci * H_ * W_;
        for (int p = t; p < TIN * TIN; p += 256) {
            int r = p / TIN, c = p - r * TIN;
            int ih = h0 + r - 1, iw = w0 + c - 1;
            float v = 0.f;
            if (ih >= 0 && ih < H_ && iw >= 0 && iw < W_) v = xc[ih * W_ + iw];
            xsm[r][c] = v;
            ssm[r][c] = v / (1.f + expf(-v));
        }
        __syncthreads();
        float xv[9], sv[9];
#pragma unroll
        for (int kh = 0; kh < 3; ++kh)
#pragma unroll
            for (int kw = 0; kw < 3; ++kw) {
                xv[kh * 3 + kw] = xsm[ty + kh][tx + kw];
                sv[kh * 3 + kw] = ssm[ty + kh][tx + kw];
            }
#pragma unroll
        for (int co = 0; co < COB; ++co) {
            const float* w1 = wsp + ((size_t)(co0 + co) * CIN + ci) * 9;
            const float* w2 = wb  + ((size_t)(co0 + co) * CIN + ci) * 9;
#pragma unroll
            for (int k = 0; k < 9; ++k)
                acc[co] += xv[k] * w1[k] + sv[k] * w2[k];
        }
    }
    const int oh = h0 + ty, ow = w0 + tx;
#pragma unroll
    for (int co = 0; co < COB; ++co)
        out[(((size_t)b * COUT + (co0 + co)) * H_ + oh) * W_ + ow] = acc[co];
}

extern "C" void kernel_launch(void* const* d_in, const int* in_sizes, int n_in,
                              void* d_out, int out_size, void* d_ws, size_t ws_size,
                              hipStream_t stream) {
    const float* x  = (const float*)d_in[0];
    const float* sw = (const float*)d_in[1];   // (COUT,CIN,3,3,4)
    const float* bw = (const float*)d_in[2];   // (COUT,CIN,3,3)
    float* out = (float*)d_out;

    if (ws_size >= WS_NEED) {
        __bf16* xt = (__bf16*)d_ws;
        __bf16* wc = (__bf16*)((char*)d_ws + XT_BYTES);
        float*  zp = (float*)((char*)d_ws + Z_OFF);
        w_prep<<<(COUT * KTOT + 255) / 256, 256, 0, stream>>>(sw, bw, wc, zp);
        xt_prep<<<dim3(2, H_, B_), 256, 0, stream>>>(x, xt);
        kan_mfma<<<dim3(1024), 256, 0, stream>>>(xt, wc, zp, out);
    } else {
        float* wsum = (float*)d_ws;
        spline_sum_kernel<<<(COUT * CIN * 9 + 255) / 256, 256, 0, stream>>>(sw, wsum);
        kan_conv<<<dim3(64, COUT / COB, B_), 256, 0, stream>>>(x, wsum, bw, out);
    }
}

// Round 14
// 113.678 us; speedup vs baseline: 9.4046x; 9.4046x over previous
//
#include <hip/hip_runtime.h>
#include <math.h>

#define B_    16
#define CIN   64
#define COUT  128
#define H_    128
#define W_    128
#define CI2   128            // 2*CIN (x ++ silu(x))
#define KTOT  1152           // 9 taps * CI2

typedef __bf16 bf16x8 __attribute__((ext_vector_type(8)));
typedef float  f32x4  __attribute__((ext_vector_type(4)));

#define XT_BYTES  ((size_t)B_ * H_ * W_ * CI2 * 2)   // 67,108,864
#define WC_BYTES  ((size_t)COUT * KTOT * 2)          // 294,912
#define Z_OFF     (XT_BYTES + WC_BYTES)
#define WS_NEED   (Z_OFF + 4096)

// ---------- prep 1: weights -> Wc, TAP-MAJOR wave-fragment order ----------
// elem index = ((tap*32 + (wm*4+m)*4 + ks)*64 + lane)*8 + e  (lane = lq*16+l15)
// -> per tap a contiguous 32KB block, stageable to LDS with linear dest.
__global__ __launch_bounds__(256) void w_prep(const float* __restrict__ sw,
                                              const float* __restrict__ bw,
                                              __bf16* __restrict__ wc,
                                              float* __restrict__ zp) {
    const int i = blockIdx.x * 256 + threadIdx.x;
    if (blockIdx.x == 0) zp[threadIdx.x] = 0.f;  // zeros page (1 KiB)
    if (i >= COUT * KTOT) return;
    const int co = i / KTOT, k = i - co * KTOT;
    const int tap = k >> 7, ci2 = k & 127;
    float v;
    if (ci2 < CIN) {
        const float* p = sw + ((size_t)(co * CIN + ci2) * 9 + tap) * 4;
        v = p[0] + p[1] + p[2] + p[3];
    } else {
        v = bw[(size_t)(co * CIN + (ci2 - CIN)) * 9 + tap];
    }
    const int wm = co >> 6, m = (co >> 4) & 3, l15 = co & 15;
    const int ks = (k >> 5) & 3, lq = (k >> 3) & 3, e = k & 7;
    const size_t off =
        ((size_t)(tap * 32 + (wm * 4 + m) * 4 + ks) * 64 + lq * 16 + l15) * 8 + e;
    wc[off] = (__bf16)v;
}

// ---------- prep 2: x (NCHW fp32) -> Xt (NHWC bf16, ci2 = x ++ silu(x)) ----------
__global__ __launch_bounds__(256) void xt_prep(const float* __restrict__ x,
                                               __bf16* __restrict__ xt) {
    __shared__ __align__(16) __bf16 tile[64][136];
    const int t  = threadIdx.x;
    const int w0 = blockIdx.x * 64;
    const int h  = blockIdx.y;
    const int b  = blockIdx.z;
    const float* xb = x + ((size_t)(b * CIN) * H_ + h) * W_ + w0;
#pragma unroll
    for (int rep = 0; rep < 16; ++rep) {
        const int idx = rep * 256 + t;
        const int ci = idx >> 6, w = idx & 63;
        const float v = xb[(size_t)ci * H_ * W_ + w];
        tile[w][ci]       = (__bf16)v;
        tile[w][CIN + ci] = (__bf16)(v / (1.f + __expf(-v)));
    }
    __syncthreads();
    __bf16* ob = xt + (((size_t)b * H_ + h) * W_ + w0) * CI2;
#pragma unroll
    for (int rep = 0; rep < 4; ++rep) {
        const int idx = rep * 256 + t;
        const int w = idx >> 4, sl = idx & 15;
        *(bf16x8*)(ob + (size_t)w * CI2 + sl * 8) = *(const bf16x8*)(&tile[w][sl * 8]);
    }
}

// ---------- main: implicit-GEMM MFMA conv, A+B both LDS-fed (m97 structure) ----------
// block: 128 couts x (8h x 16w); 4 waves 2(m) x 2(n); LDS = B halo 46KB + A tap 32KB.
// tap loop: compute ks0..3 (all-LDS reads) ; barrier ; stage A(tap+1) ; barrier.
__global__ __launch_bounds__(256, 2) void kan_mfma(const __bf16* __restrict__ xt,
                                                   const __bf16* __restrict__ wc,
                                                   const float* __restrict__ zp,
                                                   float* __restrict__ out) {
    __shared__ __align__(16) char xs[2880 * 16];    // B halo: 180 pos * 256B
    __shared__ __align__(16) char as_[2048 * 16];   // A tap buffer: 32 KB
    const int t    = threadIdx.x;
    const int lane = t & 63, wave = t >> 6;
    const int wm = wave >> 1, wn = wave & 1;
    const int l15 = lane & 15, lq = lane >> 4;

    // XCD-chunked bijective swizzle (2048 % 8 == 0)
    const int orig = blockIdx.x;
    const int wid  = (orig & 7) * 256 + (orig >> 3);
    const int b  = wid >> 7;
    const int hy = (wid & 127) >> 3, wx = wid & 7;
    const int w0 = wx * 16, h0 = hy * 8;

    // ---- stage B halo tile once (swizzled source, linear LDS dest)
    const size_t xbase = (size_t)b * (H_ * W_ * CI2);
#pragma unroll
    for (int i = 0; i < 12; ++i) {
        const int s = i * 256 + t;
        if (s < 2880) {
            const int pos = s >> 4, q = s & 15;
            const int ih = pos / 18, iw = pos - ih * 18;
            const int gh = h0 + ih - 1, gw = w0 + iw - 1;
            const int chunk = q ^ (pos & 15);
            const void* src;
            if (gh >= 0 && gh < H_ && gw >= 0 && gw < W_)
                src = (const void*)(xt + xbase + ((size_t)(gh * W_ + gw)) * CI2 + chunk * 8);
            else
                src = (const void*)zp;
            __builtin_amdgcn_global_load_lds(
                (const __attribute__((address_space(1))) unsigned int*)src,
                (__attribute__((address_space(3))) unsigned int*)(xs + s * 16), 16, 0, 0);
        }
    }

    // ---- stage A for one tap: 2048 x 16B, fully linear both sides
#define STAGEA_(tp)                                                             \
    _Pragma("unroll")                                                           \
    for (int i = 0; i < 8; ++i) {                                               \
        const int s = i * 256 + t;                                              \
        __builtin_amdgcn_global_load_lds(                                       \
            (const __attribute__((address_space(1))) unsigned int*)              \
                (wc + ((size_t)(tp) * 2048 + s) * 8),                           \
            (__attribute__((address_space(3))) unsigned int*)(as_ + s * 16),    \
            16, 0, 0);                                                          \
    }

    STAGEA_(0);
    __syncthreads();                 // B + A(0) ready

    f32x4 acc[4][4] = {};
    int pos0[4];
#pragma unroll
    for (int n = 0; n < 4; ++n) pos0[n] = (wn * 4 + n) * 18 + l15;

#pragma unroll 1
    for (int tap = 0; tap < 9; ++tap) {
        const int kh = (tap * 11) >> 5;          // tap/3 for 0..8
        const int kw = tap - kh * 3;
        const int dpos = kh * 18 + kw;
#pragma unroll
        for (int ks = 0; ks < 4; ++ks) {
            bf16x8 af[4], bfr[4];
#pragma unroll
            for (int m = 0; m < 4; ++m)
                af[m] = *(const bf16x8*)(as_ + ((wm * 4 + m) * 4 + ks) * 1024 + lane * 16);
#pragma unroll
            for (int n = 0; n < 4; ++n) {
                const int pos_ = pos0[n] + dpos;
                const int swz_ = (ks * 4 + lq) ^ (pos_ & 15);
                bfr[n] = *(const bf16x8*)(xs + pos_ * 256 + swz_ * 16);
            }
#pragma unroll
            for (int m = 0; m < 4; ++m)
#pragma unroll
                for (int n = 0; n < 4; ++n)
                    acc[m][n] = __builtin_amdgcn_mfma_f32_16x16x32_bf16(
                        af[m], bfr[n], acc[m][n], 0, 0, 0);
        }
        if (tap < 8) {
            __syncthreads();         // all waves done reading as_
            STAGEA_(tap + 1);
            __syncthreads();         // staged A visible (vmcnt drained)
        }
    }

    // ---- epilogue: D row = co (lq*4+r), col = position (l15); 64B store rows
    float* ob = out + (size_t)b * COUT * H_ * W_;
#pragma unroll
    for (int m = 0; m < 4; ++m) {
        const int co = wm * 64 + m * 16 + lq * 4;
#pragma unroll
        for (int n = 0; n < 4; ++n) {
            const int ph = wn * 4 + n;
            float* p = ob + ((size_t)co * H_ + (h0 + ph)) * W_ + (w0 + l15);
#pragma unroll
            for (int r = 0; r < 4; ++r)
                p[(size_t)r * H_ * W_] = acc[m][n][r];
        }
    }
#undef STAGEA_
}

// ---------- fallback (round-0 fp32 path, used only if ws too small) ----------
#define TS   16
#define COB  8
#define TIN  18
__global__ __launch_bounds__(256) void spline_sum_kernel(const float* __restrict__ sw,
                                                         float* __restrict__ wsum) {
    int i = blockIdx.x * 256 + threadIdx.x;
    if (i < COUT * CIN * 9) {
        const float4 v = *reinterpret_cast<const float4*>(sw + (size_t)i * 4);
        wsum[i] = v.x + v.y + v.z + v.w;
    }
}
__global__ __launch_bounds__(256) void kan_conv(const float* __restrict__ x,
                                                const float* __restrict__ wsp,
                                                const float* __restrict__ wb,
                                                float* __restrict__ out) {
    __shared__ float xsm[TIN][20];
    __shared__ float ssm[TIN][20];
    const int t = threadIdx.x, tx = t & 15, ty = t >> 4;
    const int w0 = (blockIdx.x & 7) * TS, h0 = (blockIdx.x >> 3) * TS;
    const int co0 = blockIdx.y * COB, b = blockIdx.z;
    float acc[COB];
#pragma unroll
    for (int i = 0; i < COB; ++i) acc[i] = 0.f;
    const float* xb = x + (size_t)b * CIN * H_ * W_;
    for (int ci = 0; ci < CIN; ++ci) {
        __syncthreads();
        const float* xc = xb + (size_t)ci * H_ * W_;
        for (int p = t; p < TIN * TIN; p += 256) {
            int r = p / TIN, c = p - r * TIN;
            int ih = h0 + r - 1, iw = w0 + c - 1;
            float v = 0.f;
            if (ih >= 0 && ih < H_ && iw >= 0 && iw < W_) v = xc[ih * W_ + iw];
            xsm[r][c] = v;
            ssm[r][c] = v / (1.f + expf(-v));
        }
        __syncthreads();
        float xv[9], sv[9];
#pragma unroll
        for (int kh = 0; kh < 3; ++kh)
#pragma unroll
            for (int kw = 0; kw < 3; ++kw) {
                xv[kh * 3 + kw] = xsm[ty + kh][tx + kw];
                sv[kh * 3 + kw] = ssm[ty + kh][tx + kw];
            }
#pragma unroll
        for (int co = 0; co < COB; ++co) {
            const float* w1 = wsp + ((size_t)(co0 + co) * CIN + ci) * 9;
            const float* w2 = wb  + ((size_t)(co0 + co) * CIN + ci) * 9;
#pragma unroll
            for (int k = 0; k < 9; ++k)
                acc[co] += xv[k] * w1[k] + sv[k] * w2[k];
        }
    }
    const int oh = h0 + ty, ow = w0 + tx;
#pragma unroll
    for (int co = 0; co < COB; ++co)
        out[(((size_t)b * COUT + (co0 + co)) * H_ + oh) * W_ + ow] = acc[co];
}

extern "C" void kernel_launch(void* const* d_in, const int* in_sizes, int n_in,
                              void* d_out, int out_size, void* d_ws, size_t ws_size,
                              hipStream_t stream) {
    const float* x  = (const float*)d_in[0];
    const float* sw = (const float*)d_in[1];   // (COUT,CIN,3,3,4)
    const float* bw = (const float*)d_in[2];   // (COUT,CIN,3,3)
    float* out = (float*)d_out;

    if (ws_size >= WS_NEED) {
        __bf16* xt = (__bf16*)d_ws;
        __bf16* wc = (__bf16*)((char*)d_ws + XT_BYTES);
        float*  zp = (float*)((char*)d_ws + Z_OFF);
        w_prep<<<(COUT * KTOT + 255) / 256, 256, 0, stream>>>(sw, bw, wc, zp);
        xt_prep<<<dim3(2, H_, B_), 256, 0, stream>>>(x, xt);
        kan_mfma<<<dim3(2048), 256, 0, stream>>>(xt, wc, zp, out);
    } else {
        float* wsum = (float*)d_ws;
        spline_sum_kernel<<<(COUT * CIN * 9 + 255) / 256, 256, 0, stream>>>(sw, wsum);
        kan_conv<<<dim3(64, COUT / COB, B_), 256, 0, stream>>>(x, wsum, bw, out);
    }
}